// Round 7
// baseline (188.035 us; speedup 1.0000x reference)
//
#include <hip/hip_runtime.h>
#include <hip/hip_bf16.h>
#include <math.h>

#define B_   4
#define N_   512
#define DIN  256
#define E_   64
#define H_   4

typedef __attribute__((ext_vector_type(8))) short bf16x8;
typedef __attribute__((ext_vector_type(4))) float f32x4;

__device__ __forceinline__ unsigned short f2bf(float f) {
    __hip_bfloat16 h = __float2bfloat16(f);
    return *reinterpret_cast<unsigned short*>(&h);
}

// ---------------------------------------------------------------------------
// Projection: per block Y[32 rows][64 cols] = X_tile * W + b.  grid=768.
// Outputs: p=0: Q f32 [bh][512][64] + Qp bf16 (+qn2)
//          p=1: KT f32 [bh][64][512] (LDS transpose) + Kp bf16 row-major (+kn2)
//          p=2: VTp bf16 [bh][64][512] (LDS transpose)
// ---------------------------------------------------------------------------
__global__ __launch_bounds__(256) void proj_kernel(
    const float* __restrict__ x,
    const float* __restrict__ Wq, const float* __restrict__ bq,
    const float* __restrict__ Wk, const float* __restrict__ bk,
    const float* __restrict__ Wv, const float* __restrict__ bv,
    float* __restrict__ Q, float* __restrict__ KT,
    float* __restrict__ qn2, float* __restrict__ kn2,
    unsigned short* __restrict__ Qp, unsigned short* __restrict__ Kp,
    unsigned short* __restrict__ VTp)
{
    const int tid = threadIdx.x;
    int blk = blockIdx.x;
    const int tile = blk & 15;  blk >>= 4;
    const int p    = blk % 3;   blk /= 3;
    const int h    = blk & 3;
    const int b    = blk >> 2;

    const float* W;
    const float* bias;
    if (p == 0)      { W = Wq; bias = bq; }
    else if (p == 1) { W = Wk; bias = bk; }
    else             { W = Wv; bias = bv; }
    W    += (size_t)h * DIN * E_;
    bias += h * E_;

    const int rowbase = tile * 32;
    const float* xb = x + ((size_t)b * N_ + rowbase) * DIN;

    __shared__ float XsT[64][34];
    __shared__ float Ws[64][64];
    __shared__ float Ys[64][33];    // transpose staging for KT / VT

    const int tr = tid >> 4;
    const int tc = tid & 15;

    float acc[2][4];
    #pragma unroll
    for (int i = 0; i < 2; ++i)
        #pragma unroll
        for (int j = 0; j < 4; ++j) acc[i][j] = 0.f;

    for (int dc = 0; dc < DIN; dc += 64) {
        for (int l = tid; l < 2048; l += 256) {
            int r = l >> 6, d = l & 63;
            XsT[d][r] = xb[r * DIN + dc + d];
        }
        {
            const float4* Wg4 = (const float4*)(W + (size_t)dc * E_);
            #pragma unroll
            for (int i = 0; i < 4; ++i) ((float4*)Ws)[tid + i * 256] = Wg4[tid + i * 256];
        }
        __syncthreads();

        #pragma unroll 8
        for (int d = 0; d < 64; ++d) {
            float2 xv = *(const float2*)&XsT[d][tr * 2];
            float4 wv = *(const float4*)&Ws[d][tc * 4];
            acc[0][0] = fmaf(xv.x, wv.x, acc[0][0]);
            acc[0][1] = fmaf(xv.x, wv.y, acc[0][1]);
            acc[0][2] = fmaf(xv.x, wv.z, acc[0][2]);
            acc[0][3] = fmaf(xv.x, wv.w, acc[0][3]);
            acc[1][0] = fmaf(xv.y, wv.x, acc[1][0]);
            acc[1][1] = fmaf(xv.y, wv.y, acc[1][1]);
            acc[1][2] = fmaf(xv.y, wv.z, acc[1][2]);
            acc[1][3] = fmaf(xv.y, wv.w, acc[1][3]);
        }
        __syncthreads();
    }

    const size_t bh = (size_t)b * H_ + h;
    float4 bias4 = *(const float4*)&bias[tc * 4];
    float v0[4], v1[4];
    v0[0] = acc[0][0] + bias4.x; v0[1] = acc[0][1] + bias4.y;
    v0[2] = acc[0][2] + bias4.z; v0[3] = acc[0][3] + bias4.w;
    v1[0] = acc[1][0] + bias4.x; v1[1] = acc[1][1] + bias4.y;
    v1[2] = acc[1][2] + bias4.z; v1[3] = acc[1][3] + bias4.w;

    const int r0 = rowbase + tr * 2;

    if (p < 2) {   // row squared-norms for q (p=0) and k (p=1)
        float s0 = 0.f, s1 = 0.f;
        #pragma unroll
        for (int j = 0; j < 4; ++j) {
            s0 = fmaf(v0[j], v0[j], s0);
            s1 = fmaf(v1[j], v1[j], s1);
        }
        #pragma unroll
        for (int off = 1; off < 16; off <<= 1) {
            s0 += __shfl_xor(s0, off, 64);
            s1 += __shfl_xor(s1, off, 64);
        }
        if (tc == 0) {
            float* nrm = (p == 0) ? qn2 : kn2;
            nrm[bh * N_ + r0]     = s0;
            nrm[bh * N_ + r0 + 1] = s1;
        }
        // bf16 row-major packs (Qp / Kp)
        unsigned short* pk = ((p == 0) ? Qp : Kp) + bh * (size_t)(N_ * E_);
        ushort4 u0, u1;
        u0.x = f2bf(v0[0]); u0.y = f2bf(v0[1]); u0.z = f2bf(v0[2]); u0.w = f2bf(v0[3]);
        u1.x = f2bf(v1[0]); u1.y = f2bf(v1[1]); u1.z = f2bf(v1[2]); u1.w = f2bf(v1[3]);
        *(ushort4*)&pk[(size_t)r0 * E_ + tc * 4]       = u0;
        *(ushort4*)&pk[(size_t)(r0 + 1) * E_ + tc * 4] = u1;
    }

    if (p == 0) {
        float* o = Q + bh * (size_t)(N_ * E_);
        *(float4*)&o[(size_t)r0 * E_ + tc * 4]       = make_float4(v0[0], v0[1], v0[2], v0[3]);
        *(float4*)&o[(size_t)(r0 + 1) * E_ + tc * 4] = make_float4(v1[0], v1[1], v1[2], v1[3]);
    } else {
        // transpose via LDS: Ys[e][n-local]
        #pragma unroll
        for (int j = 0; j < 4; ++j) {
            Ys[tc * 4 + j][tr * 2]     = v0[j];
            Ys[tc * 4 + j][tr * 2 + 1] = v1[j];
        }
        __syncthreads();
        const int e  = tid >> 2;
        const int n0 = (tid & 3) * 8;
        if (p == 1) {  // KT f32 (for the L1 head)
            float* o = KT + bh * (size_t)(E_ * N_) + (size_t)e * N_ + rowbase + n0;
            float4 a, c;
            a.x = Ys[e][n0 + 0]; a.y = Ys[e][n0 + 1];
            a.z = Ys[e][n0 + 2]; a.w = Ys[e][n0 + 3];
            c.x = Ys[e][n0 + 4]; c.y = Ys[e][n0 + 5];
            c.z = Ys[e][n0 + 6]; c.w = Ys[e][n0 + 7];
            *(float4*)&o[0] = a;
            *(float4*)&o[4] = c;
        } else {       // VT bf16 (PV B-fragments)
            unsigned short* o = VTp + bh * (size_t)(E_ * N_) + (size_t)e * N_ + rowbase + n0;
            ushort4 a, c;
            a.x = f2bf(Ys[e][n0 + 0]); a.y = f2bf(Ys[e][n0 + 1]);
            a.z = f2bf(Ys[e][n0 + 2]); a.w = f2bf(Ys[e][n0 + 3]);
            c.x = f2bf(Ys[e][n0 + 4]); c.y = f2bf(Ys[e][n0 + 5]);
            c.z = f2bf(Ys[e][n0 + 6]); c.w = f2bf(Ys[e][n0 + 7]);
            *(ushort4*)&o[0] = a;
            *(ushort4*)&o[4] = c;
        }
    }
}

// ---------------------------------------------------------------------------
// Attention: grid = 16 bh x 32 q-tiles = 512 blocks, 512 threads (8 waves).
// QK: wave w owns keys [w*64, w*64+64). P bf16 block-shared, XOR-swizzled.
// PV: wave = (e-tile = w&3, key-half = w>>2); 2-way LDS partial reduce.
// Heads 0/1/3: MFMA. Head 2 (L1): f32 VALU from f32 KT (1 key/lane).
// ---------------------------------------------------------------------------
#define PROW 1024   // P row stride in bytes (512 keys * bf16)

template <int HEAD>
__device__ __forceinline__ void mfma_logits(
    int w, int lane, size_t bh, int q0,
    const unsigned short* __restrict__ Qp,
    const unsigned short* __restrict__ Kp,
    const float* __restrict__ qn2, const float* __restrict__ kn2,
    char* Pb, float (*wmax)[16], float (*wsum)[16])
{
    const int g = lane >> 4, li = lane & 15;
    const int row0 = g * 4;
    const unsigned short* Qpb = Qp + bh * (N_ * E_) + (size_t)q0 * E_;
    const unsigned short* Kpb = Kp + bh * (N_ * E_);

    bf16x8 a0 = *(const bf16x8*)&Qpb[li * E_ + g * 8];
    bf16x8 a1 = *(const bf16x8*)&Qpb[li * E_ + g * 8 + 32];

    float qrow[4];
    if (HEAD == 1) {
        #pragma unroll
        for (int j = 0; j < 4; ++j) qrow[j] = rsqrtf(qn2[bh * N_ + q0 + row0 + j]);
    } else if (HEAD == 3) {
        #pragma unroll
        for (int j = 0; j < 4; ++j) qrow[j] = qn2[bh * N_ + q0 + row0 + j];
    }

    float lg[4][4];
    #pragma unroll
    for (int t = 0; t < 4; ++t) {
        const int m0 = w * 64 + t * 16;
        const unsigned short* kb = &Kpb[(size_t)(m0 + li) * E_ + g * 8];
        bf16x8 b0 = *(const bf16x8*)&kb[0];
        bf16x8 b1 = *(const bf16x8*)&kb[32];
        f32x4 acc = {0.f, 0.f, 0.f, 0.f};
        acc = __builtin_amdgcn_mfma_f32_16x16x32_bf16(a0, b0, acc, 0, 0, 0);
        acc = __builtin_amdgcn_mfma_f32_16x16x32_bf16(a1, b1, acc, 0, 0, 0);
        float kcol = 0.f, rk = 0.f;
        if (HEAD == 1) { kcol = kn2[bh * N_ + m0 + li]; rk = rsqrtf(kcol); }
        if (HEAD == 3) { kcol = kn2[bh * N_ + m0 + li]; }
        #pragma unroll
        for (int j = 0; j < 4; ++j) {
            float d = acc[j];
            if (HEAD == 0)      lg[t][j] = d * 0.125f;
            else if (HEAD == 1) lg[t][j] = d * qrow[j] * rk;
            else                lg[t][j] = -sqrtf(fmaxf(qrow[j] + kcol - 2.f * d, 0.f));
        }
    }

    // wave row-max over its 64 keys
    float mx[4];
    #pragma unroll
    for (int j = 0; j < 4; ++j) {
        float m = lg[0][j];
        #pragma unroll
        for (int t = 1; t < 4; ++t) m = fmaxf(m, lg[t][j]);
        #pragma unroll
        for (int off = 1; off < 16; off <<= 1) m = fmaxf(m, __shfl_xor(m, off, 64));
        mx[j] = m;
    }
    if (li == 0) {
        #pragma unroll
        for (int j = 0; j < 4; ++j) wmax[w][row0 + j] = mx[j];
    }
    __syncthreads();

    float gm[4];
    #pragma unroll
    for (int j = 0; j < 4; ++j) {
        float m = wmax[0][row0 + j];
        #pragma unroll
        for (int ww = 1; ww < 8; ++ww) m = fmaxf(m, wmax[ww][row0 + j]);
        gm[j] = m;
    }

    float sm[4] = {0.f, 0.f, 0.f, 0.f};
    #pragma unroll
    for (int t = 0; t < 4; ++t) {
        #pragma unroll
        for (int j = 0; j < 4; ++j) {
            const int row = row0 + j;
            const int key = w * 64 + t * 16 + li;
            float pv = __expf(lg[t][j] - gm[j]);
            sm[j] += pv;
            const int byte = (row * PROW + key * 2) ^ ((row & 7) << 4);
            *(unsigned short*)(Pb + byte) = f2bf(pv);
        }
    }
    #pragma unroll
    for (int j = 0; j < 4; ++j) {
        float s = sm[j];
        #pragma unroll
        for (int off = 1; off < 16; off <<= 1) s += __shfl_xor(s, off, 64);
        if (li == 0) wsum[w][row0 + j] = s;
    }
}

__global__ __launch_bounds__(512) void attn_kernel(
    const float* __restrict__ Qf, const float* __restrict__ KT,
    const unsigned short* __restrict__ Qp, const unsigned short* __restrict__ Kp,
    const unsigned short* __restrict__ VTp,
    const float* __restrict__ qn2, const float* __restrict__ kn2,
    float* __restrict__ out)
{
    const int tid  = threadIdx.x;
    const int w    = tid >> 6;
    const int lane = tid & 63;
    int blk = blockIdx.x;
    const int qt = blk & 31;
    const int h  = (blk >> 5) & 3;
    const int b  = blk >> 7;
    const size_t bh = (size_t)b * H_ + h;
    const int q0 = qt * 16;

    __shared__ unsigned short Plds[16 * 512];   // 16 KB, swizzled 1 KB rows
    __shared__ float part[2][16][68];
    __shared__ float wmax[8][16];
    __shared__ float wsum[8][16];
    __shared__ float q_lds[16][72];

    const int g = lane >> 4, li = lane & 15;
    char* Pb = (char*)Plds;

    if (h == 2) {
        // ---- L1 head: f32-exact VALU logits, 1 key per lane ----
        if (tid < 256) {
            const int r = tid >> 4, c = (tid & 15) * 4;
            *(float4*)&q_lds[r][c] =
                *(const float4*)&Qf[bh * (N_ * E_) + (size_t)(q0 + r) * E_ + c];
        }
        __syncthreads();

        const int n = w * 64 + lane;
        const float* kp = KT + bh * (E_ * N_) + n;
        float acc[16];
        #pragma unroll
        for (int r = 0; r < 16; ++r) acc[r] = 0.f;

        #pragma unroll
        for (int c = 0; c < 4; ++c) {
            float kk[16];
            #pragma unroll
            for (int i = 0; i < 16; ++i) kk[i] = kp[(size_t)(c * 16 + i) * N_];
            #pragma unroll
            for (int r = 0; r < 16; ++r) {
                const float* qr = &q_lds[r][c * 16];
                float4 qa = *(const float4*)&qr[0];
                float4 qb = *(const float4*)&qr[4];
                float4 qc = *(const float4*)&qr[8];
                float4 qd = *(const float4*)&qr[12];
                float qv[16] = {qa.x, qa.y, qa.z, qa.w, qb.x, qb.y, qb.z, qb.w,
                                qc.x, qc.y, qc.z, qc.w, qd.x, qd.y, qd.z, qd.w};
                #pragma unroll
                for (int i = 0; i < 16; ++i) acc[r] += fabsf(kk[i] - qv[i]);
            }
        }

        // wave min-distance per row
        #pragma unroll
        for (int r = 0; r < 16; ++r) {
            float mn = acc[r];
            #pragma unroll
            for (int off = 1; off < 64; off <<= 1) mn = fminf(mn, __shfl_xor(mn, off, 64));
            if (lane == 0) wmax[w][r] = mn;
        }
        __syncthreads();

        #pragma unroll
        for (int r = 0; r < 16; ++r) {
            float gmn = wmax[0][r];
            #pragma unroll
            for (int ww = 1; ww < 8; ++ww) gmn = fminf(gmn, wmax[ww][r]);
            float p = __expf(gmn - acc[r]);
            float s = p;
            #pragma unroll
            for (int off = 1; off < 64; off <<= 1) s += __shfl_xor(s, off, 64);
            if (lane == 0) wsum[w][r] = s;
            const int byte = (r * PROW + n * 2) ^ ((r & 7) << 4);
            *(unsigned short*)(Pb + byte) = f2bf(p);
        }
    } else if (h == 0) {
        mfma_logits<0>(w, lane, bh, q0, Qp, Kp, qn2, kn2, Pb, wmax, wsum);
    } else if (h == 1) {
        mfma_logits<1>(w, lane, bh, q0, Qp, Kp, qn2, kn2, Pb, wmax, wsum);
    } else {
        mfma_logits<3>(w, lane, bh, q0, Qp, Kp, qn2, kn2, Pb, wmax, wsum);
    }
    __syncthreads();   // P + wsum complete

    // ---- PV: wave = (e-tile, key-half). 8 MFMAs over 256 keys. ----
    {
        const int et = w & 3, kh = w >> 2;
        f32x4 acc = {0.f, 0.f, 0.f, 0.f};
        const unsigned short* Vb = VTp + bh * (E_ * N_)
                                 + (size_t)(et * 16 + li) * N_ + kh * 256;
        #pragma unroll
        for (int s = 0; s < 8; ++s) {
            const int byte = (li * PROW + (kh * 256 + s * 32 + g * 8) * 2)
                           ^ ((li & 7) << 4);
            bf16x8 pa = *(const bf16x8*)(Pb + byte);
            bf16x8 vb = *(const bf16x8*)&Vb[s * 32 + g * 8];
            acc = __builtin_amdgcn_mfma_f32_16x16x32_bf16(pa, vb, acc, 0, 0, 0);
        }
        #pragma unroll
        for (int j = 0; j < 4; ++j) part[kh][g * 4 + j][et * 16 + li] = acc[j];
    }
    __syncthreads();

    // ---- reduce partials, normalize, store ----
    #pragma unroll
    for (int k = 0; k < 2; ++k) {
        const int idx = tid + k * 512;
        const int row = idx >> 6, e = idx & 63;
        float s = part[0][row][e] + part[1][row][e];
        float rs = 0.f;
        #pragma unroll
        for (int ww = 0; ww < 8; ++ww) rs += wsum[ww][row];
        out[((size_t)b * N_ + q0 + row) * (H_ * E_) + h * E_ + e] = s / rs;
    }
}

// ---------------------------------------------------------------------------
extern "C" void kernel_launch(void* const* d_in, const int* in_sizes, int n_in,
                              void* d_out, int out_size, void* d_ws, size_t ws_size,
                              hipStream_t stream)
{
    const float* x  = (const float*)d_in[0];
    const float* Wq = (const float*)d_in[1];
    const float* bq = (const float*)d_in[2];
    const float* Wk = (const float*)d_in[3];
    const float* bk = (const float*)d_in[4];
    const float* Wv = (const float*)d_in[5];
    const float* bv = (const float*)d_in[6];
    float* out = (float*)d_out;

    const size_t qkv = (size_t)B_ * H_ * N_ * E_;   // 524288
    float* Q   = (float*)d_ws;
    float* KT  = Q + qkv;
    float* qn2 = KT + qkv;
    float* kn2 = qn2 + (size_t)B_ * H_ * N_;
    unsigned short* Qp  = (unsigned short*)(kn2 + (size_t)B_ * H_ * N_);
    unsigned short* Kp  = Qp + qkv;
    unsigned short* VTp = Kp + qkv;

    proj_kernel<<<B_ * H_ * 3 * (N_ / 32), 256, 0, stream>>>(
        x, Wq, bq, Wk, bk, Wv, bv, Q, KT, qn2, kn2, Qp, Kp, VTp);
    attn_kernel<<<B_ * H_ * (N_ / 16), 512, 0, stream>>>(
        Q, KT, Qp, Kp, VTp, qn2, kn2, out);
}

// Round 8
// 57.786 us; speedup vs baseline: 3.2540x; 3.2540x over previous
//
#include <hip/hip_runtime.h>
#include <hip/hip_bf16.h>
#include <math.h>

#define B_   4
#define N_   512
#define DIN  256
#define E_   64
#define H_   4

typedef __attribute__((ext_vector_type(8))) short bf16x8;
typedef __attribute__((ext_vector_type(8))) unsigned short u16x8;
typedef __attribute__((ext_vector_type(4))) float f32x4;

__device__ __forceinline__ unsigned short f2bf(float f) {
    __hip_bfloat16 h = __float2bfloat16(f);
    return *reinterpret_cast<unsigned short*>(&h);
}

// ---------------------------------------------------------------------------
// Projection: per block Y[32 rows][64 cols] = X_tile * W + b.  grid=768.
// Outputs (per bh):
//   p=0: Q f32 [512][64], qn2, QF bf16 fragment layout [32 qt][8 gg][16 li][8 j]
//   p=1: KT f32 [64][512] (for L1 head), kn2, KF bf16 frags (same shape as QF)
//   p=2: VF bf16 PV-fragment layout [4 et][16 kb][4 g][16 li][8 j]
// Fragment layouts make every attn MFMA operand load a coalesced
// 16B/lane x 64-lane (1KB) transaction.
// ---------------------------------------------------------------------------
__global__ __launch_bounds__(256) void proj_kernel(
    const float* __restrict__ x,
    const float* __restrict__ Wq, const float* __restrict__ bq,
    const float* __restrict__ Wk, const float* __restrict__ bk,
    const float* __restrict__ Wv, const float* __restrict__ bv,
    float* __restrict__ Q, float* __restrict__ KT,
    float* __restrict__ qn2, float* __restrict__ kn2,
    unsigned short* __restrict__ QF, unsigned short* __restrict__ KF,
    unsigned short* __restrict__ VF)
{
    const int tid = threadIdx.x;
    int blk = blockIdx.x;
    const int tile = blk & 15;  blk >>= 4;
    const int p    = blk % 3;   blk /= 3;
    const int h    = blk & 3;
    const int b    = blk >> 2;

    const float* W;
    const float* bias;
    if (p == 0)      { W = Wq; bias = bq; }
    else if (p == 1) { W = Wk; bias = bk; }
    else             { W = Wv; bias = bv; }
    W    += (size_t)h * DIN * E_;
    bias += h * E_;

    const int rowbase = tile * 32;
    const float* xb = x + ((size_t)b * N_ + rowbase) * DIN;

    __shared__ float XsT[64][34];
    __shared__ float Ws[64][64];
    __shared__ float Ys[64][33];            // KT f32 transpose staging (p==1)
    __shared__ unsigned short Vst[64][40];  // V bf16 staging (p==2)

    const int tr = tid >> 4;
    const int tc = tid & 15;

    float acc[2][4];
    #pragma unroll
    for (int i = 0; i < 2; ++i)
        #pragma unroll
        for (int j = 0; j < 4; ++j) acc[i][j] = 0.f;

    for (int dc = 0; dc < DIN; dc += 64) {
        for (int l = tid; l < 2048; l += 256) {
            int r = l >> 6, d = l & 63;
            XsT[d][r] = xb[r * DIN + dc + d];
        }
        {
            const float4* Wg4 = (const float4*)(W + (size_t)dc * E_);
            #pragma unroll
            for (int i = 0; i < 4; ++i) ((float4*)Ws)[tid + i * 256] = Wg4[tid + i * 256];
        }
        __syncthreads();

        #pragma unroll 8
        for (int d = 0; d < 64; ++d) {
            float2 xv = *(const float2*)&XsT[d][tr * 2];
            float4 wv = *(const float4*)&Ws[d][tc * 4];
            acc[0][0] = fmaf(xv.x, wv.x, acc[0][0]);
            acc[0][1] = fmaf(xv.x, wv.y, acc[0][1]);
            acc[0][2] = fmaf(xv.x, wv.z, acc[0][2]);
            acc[0][3] = fmaf(xv.x, wv.w, acc[0][3]);
            acc[1][0] = fmaf(xv.y, wv.x, acc[1][0]);
            acc[1][1] = fmaf(xv.y, wv.y, acc[1][1]);
            acc[1][2] = fmaf(xv.y, wv.z, acc[1][2]);
            acc[1][3] = fmaf(xv.y, wv.w, acc[1][3]);
        }
        __syncthreads();
    }

    const size_t bh = (size_t)b * H_ + h;
    float4 bias4 = *(const float4*)&bias[tc * 4];
    float v0[4], v1[4];
    v0[0] = acc[0][0] + bias4.x; v0[1] = acc[0][1] + bias4.y;
    v0[2] = acc[0][2] + bias4.z; v0[3] = acc[0][3] + bias4.w;
    v1[0] = acc[1][0] + bias4.x; v1[1] = acc[1][1] + bias4.y;
    v1[2] = acc[1][2] + bias4.z; v1[3] = acc[1][3] + bias4.w;

    const int r0 = rowbase + tr * 2;

    if (p < 2) {   // row squared-norms + bf16 QK fragment stores
        float s0 = 0.f, s1 = 0.f;
        #pragma unroll
        for (int j = 0; j < 4; ++j) {
            s0 = fmaf(v0[j], v0[j], s0);
            s1 = fmaf(v1[j], v1[j], s1);
        }
        #pragma unroll
        for (int off = 1; off < 16; off <<= 1) {
            s0 += __shfl_xor(s0, off, 64);
            s1 += __shfl_xor(s1, off, 64);
        }
        if (tc == 0) {
            float* nrm = (p == 0) ? qn2 : kn2;
            nrm[bh * N_ + r0]     = s0;
            nrm[bh * N_ + r0 + 1] = s1;
        }
        // fragment store: F[t][gg][li][j] = Y[row = t*16+li][e = gg*8+j]
        unsigned short* f = ((p == 0) ? QF : KF) + bh * (size_t)(N_ * E_);
        const int t_ = r0 >> 4, li = r0 & 15;
        const int gg = tc >> 1, j0 = (tc & 1) * 4;
        ushort4 u0, u1;
        u0.x = f2bf(v0[0]); u0.y = f2bf(v0[1]); u0.z = f2bf(v0[2]); u0.w = f2bf(v0[3]);
        u1.x = f2bf(v1[0]); u1.y = f2bf(v1[1]); u1.z = f2bf(v1[2]); u1.w = f2bf(v1[3]);
        *(ushort4*)&f[(size_t)((t_ * 8 + gg) * 16 + li) * 8 + j0]       = u0;
        *(ushort4*)&f[(size_t)((t_ * 8 + gg) * 16 + li + 1) * 8 + j0]   = u1;
    }

    if (p == 0) {
        float* o = Q + bh * (size_t)(N_ * E_);
        *(float4*)&o[(size_t)r0 * E_ + tc * 4]       = make_float4(v0[0], v0[1], v0[2], v0[3]);
        *(float4*)&o[(size_t)(r0 + 1) * E_ + tc * 4] = make_float4(v1[0], v1[1], v1[2], v1[3]);
    } else if (p == 1) {
        // KT f32 via LDS transpose (coalesced full-line writes)
        #pragma unroll
        for (int j = 0; j < 4; ++j) {
            Ys[tc * 4 + j][tr * 2]     = v0[j];
            Ys[tc * 4 + j][tr * 2 + 1] = v1[j];
        }
        __syncthreads();
        const int e  = tid >> 2;
        const int n0 = (tid & 3) * 8;
        float* o = KT + bh * (size_t)(E_ * N_) + (size_t)e * N_ + rowbase + n0;
        float4 a, c;
        a.x = Ys[e][n0 + 0]; a.y = Ys[e][n0 + 1];
        a.z = Ys[e][n0 + 2]; a.w = Ys[e][n0 + 3];
        c.x = Ys[e][n0 + 4]; c.y = Ys[e][n0 + 5];
        c.z = Ys[e][n0 + 6]; c.w = Ys[e][n0 + 7];
        *(float4*)&o[0] = a;
        *(float4*)&o[4] = c;
    } else {
        // V: stage bf16 in LDS, then coalesced PV-fragment stores.
        // VF[et][kb][g][li][j] = V[e = et*16+li][key = kb*32 + g*8 + j]
        #pragma unroll
        for (int j = 0; j < 4; ++j) {
            Vst[tc * 4 + j][tr * 2]     = f2bf(v0[j]);
            Vst[tc * 4 + j][tr * 2 + 1] = f2bf(v1[j]);
        }
        __syncthreads();
        const int et = tid >> 6, rem = tid & 63;
        const int g = rem >> 4, li = rem & 15;
        const int e = et * 16 + li, kb = rowbase >> 5;
        u16x8 wv8;
        #pragma unroll
        for (int j = 0; j < 8; ++j) wv8[j] = Vst[e][g * 8 + j];
        *(u16x8*)&VF[bh * (size_t)(N_ * E_)
                     + (size_t)(((et * 16 + kb) * 4 + g) * 16 + li) * 8] = wv8;
    }
}

// ---------------------------------------------------------------------------
// Attention: grid = 16 bh x 32 q-tiles = 512 blocks, 256 threads (4 waves).
// Wave w owns keys [w*128, w*128+128). All MFMA operand loads coalesced
// (fragment layouts). P bf16 in wave-private XOR-swizzled LDS.
// Heads 0/1/3: MFMA. Head 2 (L1): f32 VALU from f32 KT (coalesced).
// ---------------------------------------------------------------------------
template <int HEAD>
__device__ __forceinline__ void mfma_logits(
    int w, int lane, size_t bh, int qt, int q0,
    const unsigned short* __restrict__ QF,
    const unsigned short* __restrict__ KF,
    const float* __restrict__ qn2, const float* __restrict__ kn2,
    char* Pw, float (*wmax)[16], float (*wsum)[16])
{
    const int g = lane >> 4, li = lane & 15;
    const int row0 = g * 4;
    const unsigned short* qfb = QF + bh * (N_ * E_) + (size_t)qt * 1024;
    const unsigned short* kfb = KF + bh * (N_ * E_);

    bf16x8 a0 = *(const bf16x8*)&qfb[(g * 16 + li) * 8];
    bf16x8 a1 = *(const bf16x8*)&qfb[((g + 4) * 16 + li) * 8];

    float qrow[4];
    if (HEAD == 1) {
        #pragma unroll
        for (int j = 0; j < 4; ++j) qrow[j] = rsqrtf(qn2[bh * N_ + q0 + row0 + j]);
    } else if (HEAD == 3) {
        #pragma unroll
        for (int j = 0; j < 4; ++j) qrow[j] = qn2[bh * N_ + q0 + row0 + j];
    }

    float lg[8][4];
    #pragma unroll
    for (int t = 0; t < 8; ++t) {
        const int kt = w * 8 + t;            // key tile, 16 keys
        const int m0 = kt * 16;
        bf16x8 b0 = *(const bf16x8*)&kfb[(size_t)((kt * 8 + g) * 16 + li) * 8];
        bf16x8 b1 = *(const bf16x8*)&kfb[(size_t)((kt * 8 + g + 4) * 16 + li) * 8];
        f32x4 acc = {0.f, 0.f, 0.f, 0.f};
        acc = __builtin_amdgcn_mfma_f32_16x16x32_bf16(a0, b0, acc, 0, 0, 0);
        acc = __builtin_amdgcn_mfma_f32_16x16x32_bf16(a1, b1, acc, 0, 0, 0);
        float kcol = 0.f, rk = 0.f;
        if (HEAD == 1) { kcol = kn2[bh * N_ + m0 + li]; rk = rsqrtf(kcol); }
        if (HEAD == 3) { kcol = kn2[bh * N_ + m0 + li]; }
        #pragma unroll
        for (int j = 0; j < 4; ++j) {
            float d = acc[j];
            if (HEAD == 0)      lg[t][j] = d * 0.125f;
            else if (HEAD == 1) lg[t][j] = d * qrow[j] * rk;
            else                lg[t][j] = -sqrtf(fmaxf(qrow[j] + kcol - 2.f * d, 0.f));
        }
    }

    // wave row-max over its 128 keys
    float mx[4], gm[4];
    #pragma unroll
    for (int j = 0; j < 4; ++j) {
        float m = lg[0][j];
        #pragma unroll
        for (int t = 1; t < 8; ++t) m = fmaxf(m, lg[t][j]);
        #pragma unroll
        for (int off = 1; off < 16; off <<= 1) m = fmaxf(m, __shfl_xor(m, off, 64));
        mx[j] = m;
    }
    if (li == 0) {
        #pragma unroll
        for (int j = 0; j < 4; ++j) wmax[w][row0 + j] = mx[j];
    }
    __syncthreads();
    #pragma unroll
    for (int j = 0; j < 4; ++j)
        gm[j] = fmaxf(fmaxf(wmax[0][row0 + j], wmax[1][row0 + j]),
                      fmaxf(wmax[2][row0 + j], wmax[3][row0 + j]));

    float sm[4] = {0.f, 0.f, 0.f, 0.f};
    #pragma unroll
    for (int t = 0; t < 8; ++t) {
        #pragma unroll
        for (int j = 0; j < 4; ++j) {
            const int row = row0 + j;
            float pv = __expf(lg[t][j] - gm[j]);
            sm[j] += pv;
            const int byte = (row * 256 + (t * 16 + li) * 2) ^ ((row & 7) << 4);
            *(unsigned short*)(Pw + byte) = f2bf(pv);
        }
    }
    #pragma unroll
    for (int j = 0; j < 4; ++j) {
        float s = sm[j];
        #pragma unroll
        for (int off = 1; off < 16; off <<= 1) s += __shfl_xor(s, off, 64);
        if (li == 0) wsum[w][row0 + j] = s;
    }
}

__global__ __launch_bounds__(256) void attn_kernel(
    const float* __restrict__ Qf, const float* __restrict__ KT,
    const unsigned short* __restrict__ QF, const unsigned short* __restrict__ KF,
    const unsigned short* __restrict__ VF,
    const float* __restrict__ qn2, const float* __restrict__ kn2,
    float* __restrict__ out)
{
    const int tid  = threadIdx.x;
    const int w    = tid >> 6;
    const int lane = tid & 63;
    int blk = blockIdx.x;
    const int qt = blk & 31;
    const int h  = (blk >> 5) & 3;
    const int b  = blk >> 7;
    const size_t bh = (size_t)b * H_ + h;
    const int q0 = qt * 16;

    __shared__ unsigned short Plds[4][2048];   // per-wave [16 rows][128 keys], swizzled
    __shared__ float part[4][16][68];
    __shared__ float wmax[4][16];
    __shared__ float wsum[4][16];
    __shared__ float q_lds[16][72];

    const int g = lane >> 4, li = lane & 15;
    char* Pw = (char*)&Plds[w][0];

    if (h == 2) {
        // ---- L1 head: f32-exact VALU logits, 2 keys per lane (coalesced) ----
        {
            const int i4 = tid * 4;
            const int r = i4 >> 6, c = i4 & 63;
            *(float4*)&q_lds[r][c] =
                *(const float4*)&Qf[bh * (N_ * E_) + (size_t)(q0 + r) * E_ + c];
        }
        __syncthreads();

        float acc0[16], acc1[16];
        #pragma unroll
        for (int r = 0; r < 16; ++r) { acc0[r] = 0.f; acc1[r] = 0.f; }

        const float* kp = KT + bh * (E_ * N_) + w * 128 + 2 * lane;
        for (int c = 0; c < 4; ++c) {
            float2 kk[16];
            #pragma unroll
            for (int i = 0; i < 16; ++i) kk[i] = *(const float2*)&kp[(c * 16 + i) * N_];
            #pragma unroll
            for (int r = 0; r < 16; ++r) {
                const float* qr = &q_lds[r][c * 16];
                float4 qa = *(const float4*)&qr[0];
                float4 qb = *(const float4*)&qr[4];
                float4 qc = *(const float4*)&qr[8];
                float4 qd = *(const float4*)&qr[12];
                float qv[16] = {qa.x, qa.y, qa.z, qa.w, qb.x, qb.y, qb.z, qb.w,
                                qc.x, qc.y, qc.z, qc.w, qd.x, qd.y, qd.z, qd.w};
                #pragma unroll
                for (int i = 0; i < 16; ++i) {
                    acc0[r] += fabsf(kk[i].x - qv[i]);
                    acc1[r] += fabsf(kk[i].y - qv[i]);
                }
            }
        }

        // per-row min distance across wave, then across waves
        #pragma unroll
        for (int r = 0; r < 16; ++r) {
            float mn = fminf(acc0[r], acc1[r]);
            #pragma unroll
            for (int off = 1; off < 64; off <<= 1) mn = fminf(mn, __shfl_xor(mn, off, 64));
            if (lane == 0) wmax[w][r] = mn;
        }
        __syncthreads();
        #pragma unroll
        for (int r = 0; r < 16; ++r) {
            float gmn = fminf(fminf(wmax[0][r], wmax[1][r]), fminf(wmax[2][r], wmax[3][r]));
            float p0 = __expf(gmn - acc0[r]);
            float p1 = __expf(gmn - acc1[r]);
            float s = p0 + p1;
            #pragma unroll
            for (int off = 1; off < 64; off <<= 1) s += __shfl_xor(s, off, 64);
            if (lane == 0) wsum[w][r] = s;
            unsigned int pk = (unsigned int)f2bf(p0) | ((unsigned int)f2bf(p1) << 16);
            const int byte = (r * 256 + lane * 4) ^ ((r & 7) << 4);
            *(unsigned int*)(Pw + byte) = pk;
        }
    } else if (h == 0) {
        mfma_logits<0>(w, lane, bh, qt, q0, QF, KF, qn2, kn2, Pw, wmax, wsum);
    } else if (h == 1) {
        mfma_logits<1>(w, lane, bh, qt, q0, QF, KF, qn2, kn2, Pw, wmax, wsum);
    } else {
        mfma_logits<3>(w, lane, bh, qt, q0, QF, KF, qn2, kn2, Pw, wmax, wsum);
    }

    // ---- PV: wave-private P, fragment-coalesced V loads ----
    {
        bf16x8 pa[4];
        #pragma unroll
        for (int s = 0; s < 4; ++s) {
            const int byte = (li * 256 + (s * 32 + g * 8) * 2) ^ ((li & 7) << 4);
            pa[s] = *(const bf16x8*)(Pw + byte);
        }
        const unsigned short* vfb = VF + bh * (N_ * E_);
        const int row0 = g * 4;
        #pragma unroll
        for (int et = 0; et < 4; ++et) {
            f32x4 acc = {0.f, 0.f, 0.f, 0.f};
            #pragma unroll
            for (int s = 0; s < 4; ++s) {
                bf16x8 vb = *(const bf16x8*)&vfb[
                    (size_t)(((et * 16 + w * 4 + s) * 4 + g) * 16 + li) * 8];
                acc = __builtin_amdgcn_mfma_f32_16x16x32_bf16(pa[s], vb, acc, 0, 0, 0);
            }
            #pragma unroll
            for (int j = 0; j < 4; ++j) part[w][row0 + j][et * 16 + li] = acc[j];
        }
    }
    __syncthreads();

    // ---- reduce partials over waves, normalize, store ----
    #pragma unroll
    for (int k = 0; k < 4; ++k) {
        const int idx = tid + k * 256;
        const int row = idx >> 6, e = idx & 63;
        float s = part[0][row][e] + part[1][row][e] + part[2][row][e] + part[3][row][e];
        float rs = wsum[0][row] + wsum[1][row] + wsum[2][row] + wsum[3][row];
        out[((size_t)b * N_ + q0 + row) * (H_ * E_) + h * E_ + e] = s / rs;
    }
}

// ---------------------------------------------------------------------------
extern "C" void kernel_launch(void* const* d_in, const int* in_sizes, int n_in,
                              void* d_out, int out_size, void* d_ws, size_t ws_size,
                              hipStream_t stream)
{
    const float* x  = (const float*)d_in[0];
    const float* Wq = (const float*)d_in[1];
    const float* bq = (const float*)d_in[2];
    const float* Wk = (const float*)d_in[3];
    const float* bk = (const float*)d_in[4];
    const float* Wv = (const float*)d_in[5];
    const float* bv = (const float*)d_in[6];
    float* out = (float*)d_out;

    const size_t qkv = (size_t)B_ * H_ * N_ * E_;   // 524288
    float* Q   = (float*)d_ws;
    float* KT  = Q + qkv;
    float* qn2 = KT + qkv;
    float* kn2 = qn2 + (size_t)B_ * H_ * N_;
    unsigned short* QF = (unsigned short*)(kn2 + (size_t)B_ * H_ * N_);
    unsigned short* KF = QF + qkv;
    unsigned short* VF = KF + qkv;

    proj_kernel<<<B_ * H_ * 3 * (N_ / 32), 256, 0, stream>>>(
        x, Wq, bq, Wk, bk, Wv, bv, Q, KT, qn2, kn2, QF, KF, VF);
    attn_kernel<<<B_ * H_ * (N_ / 16), 256, 0, stream>>>(
        Q, KT, QF, KF, VF, qn2, kn2, out);
}

// Round 9
// 53.961 us; speedup vs baseline: 3.4846x; 1.0709x over previous
//
#include <hip/hip_runtime.h>
#include <hip/hip_bf16.h>
#include <math.h>

#define B_   4
#define N_   512
#define DIN  256
#define E_   64
#define H_   4

typedef __attribute__((ext_vector_type(8))) short bf16x8;
typedef __attribute__((ext_vector_type(8))) unsigned short u16x8;
typedef __attribute__((ext_vector_type(4))) float f32x4;

__device__ __forceinline__ unsigned short f2bf(float f) {
    __hip_bfloat16 h = __float2bfloat16(f);
    return *reinterpret_cast<unsigned short*>(&h);
}

// ---------------------------------------------------------------------------
// Projection: per block Y[32 rows][64 cols] = X_tile * W + b.  grid=768.
// Outputs (per bh):
//   p=0: Q f32 [512][64], qn2, QF bf16 frags [32 qt][8 gg][16 li][8 j]
//   p=1: KT f32 [64][512], kn2, KF bf16 frags (same shape as QF)
//   p=2: VF bf16 PV frags [16 kb][4 et][4 g][16 li][8 j]
// ---------------------------------------------------------------------------
__global__ __launch_bounds__(256) void proj_kernel(
    const float* __restrict__ x,
    const float* __restrict__ Wq, const float* __restrict__ bq,
    const float* __restrict__ Wk, const float* __restrict__ bk,
    const float* __restrict__ Wv, const float* __restrict__ bv,
    float* __restrict__ Q, float* __restrict__ KT,
    float* __restrict__ qn2, float* __restrict__ kn2,
    unsigned short* __restrict__ QF, unsigned short* __restrict__ KF,
    unsigned short* __restrict__ VF)
{
    const int tid = threadIdx.x;
    int blk = blockIdx.x;
    const int tile = blk & 15;  blk >>= 4;
    const int p    = blk % 3;   blk /= 3;
    const int h    = blk & 3;
    const int b    = blk >> 2;

    const float* W;
    const float* bias;
    if (p == 0)      { W = Wq; bias = bq; }
    else if (p == 1) { W = Wk; bias = bk; }
    else             { W = Wv; bias = bv; }
    W    += (size_t)h * DIN * E_;
    bias += h * E_;

    const int rowbase = tile * 32;
    const float* xb = x + ((size_t)b * N_ + rowbase) * DIN;

    __shared__ float XsT[64][34];
    __shared__ float Ws[64][64];
    __shared__ float Ys[64][33];            // KT f32 transpose staging (p==1)
    __shared__ unsigned short Vst[64][48];  // V bf16 staging (p==2), 96B rows

    const int tr = tid >> 4;
    const int tc = tid & 15;

    float acc[2][4];
    #pragma unroll
    for (int i = 0; i < 2; ++i)
        #pragma unroll
        for (int j = 0; j < 4; ++j) acc[i][j] = 0.f;

    for (int dc = 0; dc < DIN; dc += 64) {
        for (int l = tid; l < 2048; l += 256) {
            int r = l >> 6, d = l & 63;
            XsT[d][r] = xb[r * DIN + dc + d];
        }
        {
            const float4* Wg4 = (const float4*)(W + (size_t)dc * E_);
            #pragma unroll
            for (int i = 0; i < 4; ++i) ((float4*)Ws)[tid + i * 256] = Wg4[tid + i * 256];
        }
        __syncthreads();

        #pragma unroll 8
        for (int d = 0; d < 64; ++d) {
            float2 xv = *(const float2*)&XsT[d][tr * 2];
            float4 wv = *(const float4*)&Ws[d][tc * 4];
            acc[0][0] = fmaf(xv.x, wv.x, acc[0][0]);
            acc[0][1] = fmaf(xv.x, wv.y, acc[0][1]);
            acc[0][2] = fmaf(xv.x, wv.z, acc[0][2]);
            acc[0][3] = fmaf(xv.x, wv.w, acc[0][3]);
            acc[1][0] = fmaf(xv.y, wv.x, acc[1][0]);
            acc[1][1] = fmaf(xv.y, wv.y, acc[1][1]);
            acc[1][2] = fmaf(xv.y, wv.z, acc[1][2]);
            acc[1][3] = fmaf(xv.y, wv.w, acc[1][3]);
        }
        __syncthreads();
    }

    const size_t bh = (size_t)b * H_ + h;
    float4 bias4 = *(const float4*)&bias[tc * 4];
    float v0[4], v1[4];
    v0[0] = acc[0][0] + bias4.x; v0[1] = acc[0][1] + bias4.y;
    v0[2] = acc[0][2] + bias4.z; v0[3] = acc[0][3] + bias4.w;
    v1[0] = acc[1][0] + bias4.x; v1[1] = acc[1][1] + bias4.y;
    v1[2] = acc[1][2] + bias4.z; v1[3] = acc[1][3] + bias4.w;

    const int r0 = rowbase + tr * 2;

    if (p < 2) {   // row squared-norms + bf16 QK fragment stores
        float s0 = 0.f, s1 = 0.f;
        #pragma unroll
        for (int j = 0; j < 4; ++j) {
            s0 = fmaf(v0[j], v0[j], s0);
            s1 = fmaf(v1[j], v1[j], s1);
        }
        #pragma unroll
        for (int off = 1; off < 16; off <<= 1) {
            s0 += __shfl_xor(s0, off, 64);
            s1 += __shfl_xor(s1, off, 64);
        }
        if (tc == 0) {
            float* nrm = (p == 0) ? qn2 : kn2;
            nrm[bh * N_ + r0]     = s0;
            nrm[bh * N_ + r0 + 1] = s1;
        }
        // fragment store: F[t][gg][li][j] = Y[row = t*16+li][e = gg*8+j]
        unsigned short* f = ((p == 0) ? QF : KF) + bh * (size_t)(N_ * E_);
        const int t_ = r0 >> 4, li = r0 & 15;
        const int gg = tc >> 1, j0 = (tc & 1) * 4;
        ushort4 u0, u1;
        u0.x = f2bf(v0[0]); u0.y = f2bf(v0[1]); u0.z = f2bf(v0[2]); u0.w = f2bf(v0[3]);
        u1.x = f2bf(v1[0]); u1.y = f2bf(v1[1]); u1.z = f2bf(v1[2]); u1.w = f2bf(v1[3]);
        *(ushort4*)&f[(size_t)((t_ * 8 + gg) * 16 + li) * 8 + j0]       = u0;
        *(ushort4*)&f[(size_t)((t_ * 8 + gg) * 16 + li + 1) * 8 + j0]   = u1;
    }

    if (p == 0) {
        float* o = Q + bh * (size_t)(N_ * E_);
        *(float4*)&o[(size_t)r0 * E_ + tc * 4]       = make_float4(v0[0], v0[1], v0[2], v0[3]);
        *(float4*)&o[(size_t)(r0 + 1) * E_ + tc * 4] = make_float4(v1[0], v1[1], v1[2], v1[3]);
    } else if (p == 1) {
        // KT f32 via LDS transpose (coalesced full-line writes)
        #pragma unroll
        for (int j = 0; j < 4; ++j) {
            Ys[tc * 4 + j][tr * 2]     = v0[j];
            Ys[tc * 4 + j][tr * 2 + 1] = v1[j];
        }
        __syncthreads();
        const int e  = tid >> 2;
        const int n0 = (tid & 3) * 8;
        float* o = KT + bh * (size_t)(E_ * N_) + (size_t)e * N_ + rowbase + n0;
        float4 a, c;
        a.x = Ys[e][n0 + 0]; a.y = Ys[e][n0 + 1];
        a.z = Ys[e][n0 + 2]; a.w = Ys[e][n0 + 3];
        c.x = Ys[e][n0 + 4]; c.y = Ys[e][n0 + 5];
        c.z = Ys[e][n0 + 6]; c.w = Ys[e][n0 + 7];
        *(float4*)&o[0] = a;
        *(float4*)&o[4] = c;
    } else {
        // V: stage bf16, then PV-frag stores. VF[kb][et][g][li][j],
        // key = kb*32 + g*8 + j, e = et*16 + li.  kb = tile.
        #pragma unroll
        for (int j = 0; j < 4; ++j) {
            Vst[tc * 4 + j][tr * 2]     = f2bf(v0[j]);
            Vst[tc * 4 + j][tr * 2 + 1] = f2bf(v1[j]);
        }
        __syncthreads();
        const int et = tid >> 6, g = (tid >> 4) & 3, li = tid & 15;
        u16x8 wv8 = *(const u16x8*)&Vst[et * 16 + li][g * 8];
        *(u16x8*)&VF[bh * (size_t)(N_ * E_)
                     + (size_t)((((tile * 4 + et) * 4 + g) * 16) + li) * 8] = wv8;
    }
}

// ---------------------------------------------------------------------------
// attn_partial: grid = 16 bh x 32 qt x 4 kh = 2048 blocks, 256 thr (4 waves).
// Wave w owns keys [kh*128 + w*32, +32). Per-wave: QK (4 MFMA) -> in-register
// softmax over 32 keys -> P in wave-private swizzled LDS -> PV (4 MFMA) ->
// per-wave partial (O[16][64] frag-layout, m[16], s[16]). One barrier.
// ---------------------------------------------------------------------------
template <int HEAD>
__device__ __forceinline__ void mfma_logits32(
    int w, int kh, int lane, size_t bh, int qt, int q0, int pid,
    const unsigned short* __restrict__ QF,
    const unsigned short* __restrict__ KF,
    const float* __restrict__ qn2, const float* __restrict__ kn2,
    char* Pw, float* __restrict__ Mpart, float* __restrict__ Spart)
{
    const int g = lane >> 4, li = lane & 15;
    const int row0 = g * 4;
    const unsigned short* qfb = QF + bh * (N_ * E_) + (size_t)qt * 1024;
    const unsigned short* kfb = KF + bh * (N_ * E_);

    bf16x8 a0 = *(const bf16x8*)&qfb[(g * 16 + li) * 8];
    bf16x8 a1 = *(const bf16x8*)&qfb[((g + 4) * 16 + li) * 8];

    float qrow[4];
    if (HEAD == 1) {
        #pragma unroll
        for (int j = 0; j < 4; ++j) qrow[j] = rsqrtf(qn2[bh * N_ + q0 + row0 + j]);
    } else if (HEAD == 3) {
        #pragma unroll
        for (int j = 0; j < 4; ++j) qrow[j] = qn2[bh * N_ + q0 + row0 + j];
    }

    float lg[2][4];
    #pragma unroll
    for (int t = 0; t < 2; ++t) {
        const int kt = (kh * 4 + w) * 2 + t;       // global 16-key tile
        const int m0 = kt * 16;
        bf16x8 b0 = *(const bf16x8*)&kfb[(size_t)((kt * 8 + g) * 16 + li) * 8];
        bf16x8 b1 = *(const bf16x8*)&kfb[(size_t)((kt * 8 + g + 4) * 16 + li) * 8];
        f32x4 acc = {0.f, 0.f, 0.f, 0.f};
        acc = __builtin_amdgcn_mfma_f32_16x16x32_bf16(a0, b0, acc, 0, 0, 0);
        acc = __builtin_amdgcn_mfma_f32_16x16x32_bf16(a1, b1, acc, 0, 0, 0);
        float kcol = 0.f, rk = 0.f;
        if (HEAD == 1) { kcol = kn2[bh * N_ + m0 + li]; rk = rsqrtf(kcol); }
        if (HEAD == 3) { kcol = kn2[bh * N_ + m0 + li]; }
        #pragma unroll
        for (int j = 0; j < 4; ++j) {
            float d = acc[j];
            if (HEAD == 0)      lg[t][j] = d * 0.125f;
            else if (HEAD == 1) lg[t][j] = d * qrow[j] * rk;
            else                lg[t][j] = -sqrtf(fmaxf(qrow[j] + kcol - 2.f * d, 0.f));
        }
    }

    // per-row max over this wave's 32 keys
    float mx[4];
    #pragma unroll
    for (int j = 0; j < 4; ++j) {
        float m = fmaxf(lg[0][j], lg[1][j]);
        #pragma unroll
        for (int off = 1; off < 16; off <<= 1) m = fmaxf(m, __shfl_xor(m, off, 64));
        mx[j] = m;
    }

    float sm[4] = {0.f, 0.f, 0.f, 0.f};
    #pragma unroll
    for (int t = 0; t < 2; ++t) {
        #pragma unroll
        for (int j = 0; j < 4; ++j) {
            const int row = row0 + j;
            float pv = __expf(lg[t][j] - mx[j]);
            sm[j] += pv;
            const int byte = (row * 64 + (t * 16 + li) * 2) ^ ((row & 7) << 4);
            *(unsigned short*)(Pw + byte) = f2bf(pv);
        }
    }
    #pragma unroll
    for (int j = 0; j < 4; ++j) {
        float s = sm[j];
        #pragma unroll
        for (int off = 1; off < 16; off <<= 1) s += __shfl_xor(s, off, 64);
        if (li == 0) {
            Mpart[(size_t)pid * 16 + row0 + j] = mx[j];
            Spart[(size_t)pid * 16 + row0 + j] = s;
        }
    }
}

__global__ __launch_bounds__(256) void attn_partial(
    const float* __restrict__ Qf, const float* __restrict__ KT,
    const unsigned short* __restrict__ QF, const unsigned short* __restrict__ KF,
    const unsigned short* __restrict__ VF,
    const float* __restrict__ qn2, const float* __restrict__ kn2,
    float* __restrict__ Opart, float* __restrict__ Mpart,
    float* __restrict__ Spart)
{
    const int tid  = threadIdx.x;
    const int w    = tid >> 6;
    const int lane = tid & 63;
    const int blk  = blockIdx.x;
    const int kh = blk & 3;
    const int qt = (blk >> 2) & 31;
    const int bh = blk >> 7;
    const size_t bhs = (size_t)bh;
    const int q0 = qt * 16;
    const int pid = blk * 4 + w;

    __shared__ unsigned short Plds[4][512];   // per-wave [16 rows][32 keys], swizzled
    __shared__ float q_lds[16][68];

    const int g = lane >> 4, li = lane & 15;
    char* Pw = (char*)&Plds[w][0];
    const int h = bh & 3;

    if (h == 2) {
        // ---- L1 head, f32 exact: wave w covers 32 keys; half-wave = 8 rows ----
        {
            const int r = tid >> 4, c0 = (tid & 15) * 4;
            *(float4*)&q_lds[r][c0] =
                *(const float4*)&Qf[bhs * (N_ * E_) + (size_t)(q0 + r) * E_ + c0];
        }
        __syncthreads();

        const int half = lane >> 5;            // 0: rows 0-7, 1: rows 8-15
        const int kloc = lane & 31;
        const int key  = kh * 128 + w * 32 + kloc;
        const float* kp = KT + bhs * (E_ * N_) + key;

        float acc[8];
        #pragma unroll
        for (int i = 0; i < 8; ++i) acc[i] = 0.f;

        #pragma unroll 4
        for (int ec = 0; ec < 16; ++ec) {
            float k0 = kp[(size_t)(ec * 4 + 0) * N_];
            float k1 = kp[(size_t)(ec * 4 + 1) * N_];
            float k2 = kp[(size_t)(ec * 4 + 2) * N_];
            float k3 = kp[(size_t)(ec * 4 + 3) * N_];
            #pragma unroll
            for (int i = 0; i < 8; ++i) {
                float4 q4 = *(const float4*)&q_lds[half * 8 + i][ec * 4];
                acc[i] += fabsf(k0 - q4.x) + fabsf(k1 - q4.y)
                        + fabsf(k2 - q4.z) + fabsf(k3 - q4.w);
            }
        }

        #pragma unroll
        for (int i = 0; i < 8; ++i) {
            const int row = half * 8 + i;
            float mn = acc[i];
            #pragma unroll
            for (int off = 1; off < 32; off <<= 1) mn = fminf(mn, __shfl_xor(mn, off, 64));
            float m = -mn;                      // max logit
            float p = __expf(mn - acc[i]);
            float s = p;
            #pragma unroll
            for (int off = 1; off < 32; off <<= 1) s += __shfl_xor(s, off, 64);
            const int byte = (row * 64 + kloc * 2) ^ ((row & 7) << 4);
            *(unsigned short*)(Pw + byte) = f2bf(p);
            if (kloc == 0) {
                Mpart[(size_t)pid * 16 + row] = m;
                Spart[(size_t)pid * 16 + row] = s;
            }
        }
    } else if (h == 0) {
        mfma_logits32<0>(w, kh, lane, bhs, qt, q0, pid, QF, KF, qn2, kn2, Pw, Mpart, Spart);
    } else if (h == 1) {
        mfma_logits32<1>(w, kh, lane, bhs, qt, q0, pid, QF, KF, qn2, kn2, Pw, Mpart, Spart);
    } else {
        mfma_logits32<3>(w, kh, lane, bhs, qt, q0, pid, QF, KF, qn2, kn2, Pw, Mpart, Spart);
    }
    __syncthreads();   // P complete (also covers cross-half LDS visibility)

    // ---- PV: 1 MFMA per e-tile, K=32 = this wave's keys ----
    {
        const int byte = (li * 64 + g * 16) ^ ((li & 7) << 4);
        bf16x8 pa = *(const bf16x8*)(Pw + byte);
        const int kb = kh * 4 + w;
        const unsigned short* vfb = VF + bhs * (N_ * E_);
        #pragma unroll
        for (int et = 0; et < 4; ++et) {
            f32x4 acc = {0.f, 0.f, 0.f, 0.f};
            bf16x8 vb = *(const bf16x8*)&vfb[
                (size_t)((((kb * 4 + et) * 4 + g) * 16) + li) * 8];
            acc = __builtin_amdgcn_mfma_f32_16x16x32_bf16(pa, vb, acc, 0, 0, 0);
            *(f32x4*)&Opart[(size_t)pid * 1024 + ((et * 4 + g) * 16 + li) * 4] = acc;
        }
    }
}

// ---------------------------------------------------------------------------
// combine: grid = 16 bh x 32 qt = 512 blocks, 256 thr. Merges 16 wave-partials
// (disjoint 32-key chunks) with max-rescale; coalesced output via LDS.
// ---------------------------------------------------------------------------
__global__ __launch_bounds__(256) void combine_kernel(
    const float* __restrict__ Opart, const float* __restrict__ Mpart,
    const float* __restrict__ Spart, float* __restrict__ out)
{
    const int tid = threadIdx.x;
    const int blk = blockIdx.x;          // bh*32 + qt
    const int qt = blk & 31, bh = blk >> 5;
    const int b = bh >> 2, h = bh & 3;
    const int base = blk * 16;

    __shared__ float ms[16][16], ss[16][16], wls[16][16];
    __shared__ float sginv[16];
    __shared__ float Ot[16][68];

    {
        const int p = tid >> 4, row = tid & 15;
        ms[p][row] = Mpart[(size_t)(base + p) * 16 + row];
        ss[p][row] = Spart[(size_t)(base + p) * 16 + row];
    }
    __syncthreads();
    {
        const int p = tid >> 4, row = tid & 15;
        float mg = ms[0][row];
        #pragma unroll
        for (int q = 1; q < 16; ++q) mg = fmaxf(mg, ms[q][row]);
        wls[p][row] = __expf(ms[p][row] - mg);
    }
    __syncthreads();
    if (tid < 16) {
        float s = 0.f;
        #pragma unroll
        for (int p = 0; p < 16; ++p) s += wls[p][tid] * ss[p][tid];
        sginv[tid] = 1.f / s;
    }
    __syncthreads();

    {
        const int et = tid >> 6, g = (tid >> 4) & 3, li = tid & 15;
        float o0 = 0.f, o1 = 0.f, o2 = 0.f, o3 = 0.f;
        const float* op = Opart + (size_t)base * 1024 + ((et * 4 + g) * 16 + li) * 4;
        #pragma unroll
        for (int p = 0; p < 16; ++p) {
            float4 v = *(const float4*)(op + (size_t)p * 1024);
            o0 = fmaf(wls[p][g * 4 + 0], v.x, o0);
            o1 = fmaf(wls[p][g * 4 + 1], v.y, o1);
            o2 = fmaf(wls[p][g * 4 + 2], v.z, o2);
            o3 = fmaf(wls[p][g * 4 + 3], v.w, o3);
        }
        Ot[g * 4 + 0][et * 16 + li] = o0 * sginv[g * 4 + 0];
        Ot[g * 4 + 1][et * 16 + li] = o1 * sginv[g * 4 + 1];
        Ot[g * 4 + 2][et * 16 + li] = o2 * sginv[g * 4 + 2];
        Ot[g * 4 + 3][et * 16 + li] = o3 * sginv[g * 4 + 3];
    }
    __syncthreads();
    {
        const int row = tid >> 4, e0 = (tid & 15) * 4;
        const int n = qt * 16 + row;
        *(float4*)&out[((size_t)b * N_ + n) * (H_ * E_) + h * E_ + e0] =
            *(const float4*)&Ot[row][e0];
    }
}

// ---------------------------------------------------------------------------
extern "C" void kernel_launch(void* const* d_in, const int* in_sizes, int n_in,
                              void* d_out, int out_size, void* d_ws, size_t ws_size,
                              hipStream_t stream)
{
    const float* x  = (const float*)d_in[0];
    const float* Wq = (const float*)d_in[1];
    const float* bq = (const float*)d_in[2];
    const float* Wk = (const float*)d_in[3];
    const float* bk = (const float*)d_in[4];
    const float* Wv = (const float*)d_in[5];
    const float* bv = (const float*)d_in[6];
    float* out = (float*)d_out;

    const size_t qkv = (size_t)B_ * H_ * N_ * E_;   // 524288
    float* Q     = (float*)d_ws;
    float* KT    = Q + qkv;
    float* qn2   = KT + qkv;
    float* kn2   = qn2 + (size_t)B_ * H_ * N_;
    float* Opart = kn2 + (size_t)B_ * H_ * N_;      // 8192 * 1024 f32 = 32 MB
    float* Mpart = Opart + (size_t)8192 * 1024;
    float* Spart = Mpart + (size_t)8192 * 16;
    unsigned short* QF = (unsigned short*)(Spart + (size_t)8192 * 16);
    unsigned short* KF = QF + qkv;
    unsigned short* VF = KF + qkv;

    proj_kernel<<<B_ * H_ * 3 * (N_ / 32), 256, 0, stream>>>(
        x, Wq, bq, Wk, bk, Wv, bv, Q, KT, qn2, kn2, QF, KF, VF);
    attn_partial<<<B_ * H_ * 32 * 4, 256, 0, stream>>>(
        Q, KT, QF, KF, VF, qn2, kn2, Opart, Mpart, Spart);
    combine_kernel<<<B_ * H_ * 32, 256, 0, stream>>>(Opart, Mpart, Spart, out);
}